// Round 7
// baseline (250.714 us; speedup 1.0000x reference)
//
#include <hip/hip_runtime.h>
#include <math.h>

typedef _Float16 half4_t __attribute__((ext_vector_type(4)));
typedef _Float16 half8_t __attribute__((ext_vector_type(8)));
typedef __fp16   fp16x2  __attribute__((ext_vector_type(2)));
typedef float    f32x4   __attribute__((ext_vector_type(4)));

#define B_   32
#define NQ_  16384
#define NK_  31
#define DM_  64
#define BLK_PER_B 32      // 1024 blocks total
#define PAIRS 4           // 8 tiles per wave, processed as 4 dual-tile pairs
#define KSCALE 0.3606738222635048f   // 0.25 * log2(e): GEMM1 outputs log2-domain scores

static __device__ __forceinline__ half4_t cvt4(f32x4 f) {
  fp16x2 lo = __builtin_amdgcn_cvt_pkrtz(f[0], f[1]);
  fp16x2 hi = __builtin_amdgcn_cvt_pkrtz(f[2], f[3]);
  half4_t r;
  r[0] = (_Float16)lo[0]; r[1] = (_Float16)lo[1];
  r[2] = (_Float16)hi[0]; r[3] = (_Float16)hi[1];
  return r;
}

// ---------------------------------------------------------------------------
// Fused MHA + out-proj. Block = 4 waves, 16 KB LDS (VW^T frags only).
// R0-R6 post-mortem: every TLP/scheduling/coalescing lever (occupancy 18-36%,
// LDS staging, prefetch rings, reg budgets) moved dur <7% -- the limiter is
// the per-wave serial chain (~2-3k cyc latency/tile vs ~1k issue), and the HW
// never gave enough independent waves to hide it. This version buys ILP
// INSIDE the wave: each wave computes TWO independent query tiles at once,
// chains interleaved per-head, sharing one set of VW^T LDS reads between both
// tiles. Chain also shortened: kf in registers (no LDS hop), direct
// fragment-layout global access (drops 16 DS ops + 2 lgkmcnt waits/tile;
// R5 measured the coalescing detour worth only ~5%), GEMM2 runs per-head so
// softmax(h) overlaps GEMM2 MFMAs of h-1. Compiler cannot undo explicit
// dual-chain ILP (it's in the dependence graph, not the schedule).
// Causal tell: VGPR >= 130 means dual state is live.
// ---------------------------------------------------------------------------
__global__ __launch_bounds__(256, 3) void attn(
    const float* __restrict__ Q, const float* __restrict__ K,
    const float* __restrict__ V, const unsigned char* __restrict__ mraw,
    const float* __restrict__ W, const float* __restrict__ bout,
    float* __restrict__ out) {
  int b    = blockIdx.x >> 5;             // 32 blocks per batch
  int blk  = blockIdx.x & 31;
  int tid  = threadIdx.x;
  int wave = tid >> 6, lane = tid & 63;
  int lq = lane & 15, quad = lane >> 4;

  // [s][pair][lane] : 16B per lane = {vw_dt(2p), vw_dt(2p+1)}
  __shared__ half8_t lds_vw[8][2][64];

  const f32x4 fzero = {0.f, 0.f, 0.f, 0.f};

  int w = blk * 4 + wave;                 // 0..127 within batch
  const float* qrow = Q + ((size_t)b * NQ_ + lq) * DM_ + 4 * quad;

  // ---- pair-0 Q loads (tiles 0,1), fragment layout ----
  f32x4 qA[4], qB[4];
  #pragma unroll
  for (int h = 0; h < 4; ++h) {
    qA[h] = *(const f32x4*)(qrow + (size_t)(w * 16) * DM_ + 16 * h);
    qB[h] = *(const f32x4*)(qrow + (size_t)((w + 128) * 16) * DM_ + 16 * h);
  }

  // ---- mask word (per-wave, ballot-based; dtype sniffed from raw bytes) ----
  unsigned mb;
  {
    unsigned char c0 = 0, c1 = 0;
    if (lane < 62) { c0 = mraw[2 * lane]; c1 = mraw[2 * lane + 1]; }
    unsigned long long m3f =
        __ballot(lane < 62 && (c0 == 0x3f || c1 == 0x3f));
    unsigned long long moff =
        __ballot(lane < 62 && ((((2 * lane) & 3) != 0 && c0 != 0) || c1 != 0));
    int mode = m3f ? 2 : (moff ? 0 : 1);
    int nz = 0;
    if (lane < NK_) {
      int idx = b * NK_ + lane;
      nz = (mode == 0) ? (mraw[idx] != 0)
         : (mode == 1) ? (((const int*)mraw)[idx] != 0)
                       : (((const float*)mraw)[idx] != 0.0f);
    }
    mb = (unsigned)__ballot(nz) & 0x7fffffffu;
  }

  // ---- mask bias for GEMM1's C operand (key 31 pad auto-masked) ----
  f32x4 cbias[2];
  #pragma unroll
  for (int tt = 0; tt < 2; ++tt)
    #pragma unroll
    for (int r = 0; r < 4; ++r) {
      int key = 16 * tt + 4 * quad + r;
      cbias[tt][r] = ((mb >> key) & 1u) ? 0.0f : -1e30f;
    }

  // ---- K fragments in registers (16 VGPR), scale folded ----
  half4_t kf[2][4];
  #pragma unroll
  for (int tt = 0; tt < 2; ++tt) {
    int k = 16 * tt + lq;
    #pragma unroll
    for (int h = 0; h < 4; ++h) {
      f32x4 f = fzero;
      if (k < NK_)
        f = *(const f32x4*)(K + ((size_t)b * NK_ + k) * DM_ + 16 * h + 4 * quad);
      kf[tt][h] = cvt4(f * KSCALE);
    }
  }

  // ---- VW^T fragments for dt = wave (8 prologue MFMAs) -> LDS ----
  {
    half4_t af[8];
    #pragma unroll
    for (int s = 0; s < 8; ++s) {
      int k = 16 * (s & 1) + lq, h = s >> 1;
      f32x4 f = fzero;
      if (k < NK_)
        f = *(const f32x4*)(V + ((size_t)b * NK_ + k) * DM_ + 16 * h + 4 * quad);
      af[s] = cvt4(f);
    }
    half4_t bf[4];
    #pragma unroll
    for (int h = 0; h < 4; ++h) {
      f32x4 f = *(const f32x4*)(W + (16 * wave + lq) * DM_ + 16 * h + 4 * quad);
      bf[h] = cvt4(f);
    }
    #pragma unroll
    for (int s = 0; s < 8; ++s) {
      f32x4 m = __builtin_amdgcn_mfma_f32_16x16x16f16(af[s], bf[s >> 1],
                                                      fzero, 0, 0, 0);
      ((half4_t*)&lds_vw[s][wave >> 1][lane])[wave & 1] = cvt4(m);
    }
  }

  // ---- bias fragments; GEMM2's C-operand init (const across queries) ----
  f32x4 bias[4];
  #pragma unroll
  for (int dt = 0; dt < 4; ++dt)
    bias[dt] = *(const f32x4*)(bout + 16 * dt + 4 * quad);

  __syncthreads();

  // ---- main loop: 4 pairs, fully unrolled, two independent chains/pair ----
  #pragma unroll
  for (int p = 0; p < PAIRS; ++p) {
    // consume current pair into f16 fragments
    half4_t qfA[4], qfB[4];
    #pragma unroll
    for (int h = 0; h < 4; ++h) { qfA[h] = cvt4(qA[h]); qfB[h] = cvt4(qB[h]); }

    // prefetch next pair (best effort; ILP below does not depend on it)
    f32x4 qnA[4], qnB[4];
    if (p + 1 < PAIRS) {
      #pragma unroll
      for (int h = 0; h < 4; ++h) {
        qnA[h] = *(const f32x4*)(
            qrow + (size_t)((w + (2 * p + 2) * 128) * 16) * DM_ + 16 * h);
        qnB[h] = *(const f32x4*)(
            qrow + (size_t)((w + (2 * p + 3) * 128) * 16) * DM_ + 16 * h);
      }
    }

    f32x4 accA[4] = {bias[0], bias[1], bias[2], bias[3]};
    f32x4 accB[4] = {bias[0], bias[1], bias[2], bias[3]};

    #pragma unroll
    for (int h = 0; h < 4; ++h) {
      // GEMM1, both tiles (4 independent MFMAs)
      f32x4 c0A = __builtin_amdgcn_mfma_f32_16x16x16f16(kf[0][h], qfA[h], cbias[0], 0, 0, 0);
      f32x4 c1A = __builtin_amdgcn_mfma_f32_16x16x16f16(kf[1][h], qfA[h], cbias[1], 0, 0, 0);
      f32x4 c0B = __builtin_amdgcn_mfma_f32_16x16x16f16(kf[0][h], qfB[h], cbias[0], 0, 0, 0);
      f32x4 c1B = __builtin_amdgcn_mfma_f32_16x16x16f16(kf[1][h], qfB[h], cbias[1], 0, 0, 0);

      // softmax, both tiles (independent chains interleave)
      f32x4 e0A, e1A, e0B, e1B;
      #pragma unroll
      for (int r = 0; r < 4; ++r) {
        e0A[r] = __builtin_amdgcn_exp2f(c0A[r]);
        e1A[r] = __builtin_amdgcn_exp2f(c1A[r]);
        e0B[r] = __builtin_amdgcn_exp2f(c0B[r]);
        e1B[r] = __builtin_amdgcn_exp2f(c1B[r]);
      }
      float sA = (e0A[0] + e0A[1]) + (e0A[2] + e0A[3]) +
                 (e1A[0] + e1A[1]) + (e1A[2] + e1A[3]);
      float sB = (e0B[0] + e0B[1]) + (e0B[2] + e0B[3]) +
                 (e1B[0] + e1B[1]) + (e1B[2] + e1B[3]);
      sA += __shfl_xor(sA, 16);  sB += __shfl_xor(sB, 16);
      sA += __shfl_xor(sA, 32);  sB += __shfl_xor(sB, 32);
      float iA = (sA > 0.f) ? __builtin_amdgcn_rcpf(sA) : 0.f;
      float iB = (sB > 0.f) ? __builtin_amdgcn_rcpf(sB) : 0.f;
      half4_t pA0 = cvt4(e0A * iA), pA1 = cvt4(e1A * iA);
      half4_t pB0 = cvt4(e0B * iB), pB1 = cvt4(e1B * iB);

      // VW^T frags for s=2h,2h+1 read ONCE, shared by both tiles
      half8_t u0 = lds_vw[2 * h + 0][0][lane];
      half8_t u1 = lds_vw[2 * h + 0][1][lane];
      half8_t v0 = lds_vw[2 * h + 1][0][lane];
      half8_t v1 = lds_vw[2 * h + 1][1][lane];
      half4_t s0d0 = __builtin_shufflevector(u0, u0, 0, 1, 2, 3);
      half4_t s0d1 = __builtin_shufflevector(u0, u0, 4, 5, 6, 7);
      half4_t s0d2 = __builtin_shufflevector(u1, u1, 0, 1, 2, 3);
      half4_t s0d3 = __builtin_shufflevector(u1, u1, 4, 5, 6, 7);
      half4_t s1d0 = __builtin_shufflevector(v0, v0, 0, 1, 2, 3);
      half4_t s1d1 = __builtin_shufflevector(v0, v0, 4, 5, 6, 7);
      half4_t s1d2 = __builtin_shufflevector(v1, v1, 0, 1, 2, 3);
      half4_t s1d3 = __builtin_shufflevector(v1, v1, 4, 5, 6, 7);

      // GEMM2 for head h, both tiles (16 MFMAs, 2 indep chains x 4 dt)
      accA[0] = __builtin_amdgcn_mfma_f32_16x16x16f16(s0d0, pA0, accA[0], 0, 0, 0);
      accA[1] = __builtin_amdgcn_mfma_f32_16x16x16f16(s0d1, pA0, accA[1], 0, 0, 0);
      accA[2] = __builtin_amdgcn_mfma_f32_16x16x16f16(s0d2, pA0, accA[2], 0, 0, 0);
      accA[3] = __builtin_amdgcn_mfma_f32_16x16x16f16(s0d3, pA0, accA[3], 0, 0, 0);
      accB[0] = __builtin_amdgcn_mfma_f32_16x16x16f16(s0d0, pB0, accB[0], 0, 0, 0);
      accB[1] = __builtin_amdgcn_mfma_f32_16x16x16f16(s0d1, pB0, accB[1], 0, 0, 0);
      accB[2] = __builtin_amdgcn_mfma_f32_16x16x16f16(s0d2, pB0, accB[2], 0, 0, 0);
      accB[3] = __builtin_amdgcn_mfma_f32_16x16x16f16(s0d3, pB0, accB[3], 0, 0, 0);
      accA[0] = __builtin_amdgcn_mfma_f32_16x16x16f16(s1d0, pA1, accA[0], 0, 0, 0);
      accA[1] = __builtin_amdgcn_mfma_f32_16x16x16f16(s1d1, pA1, accA[1], 0, 0, 0);
      accA[2] = __builtin_amdgcn_mfma_f32_16x16x16f16(s1d2, pA1, accA[2], 0, 0, 0);
      accA[3] = __builtin_amdgcn_mfma_f32_16x16x16f16(s1d3, pA1, accA[3], 0, 0, 0);
      accB[0] = __builtin_amdgcn_mfma_f32_16x16x16f16(s1d0, pB1, accB[0], 0, 0, 0);
      accB[1] = __builtin_amdgcn_mfma_f32_16x16x16f16(s1d1, pB1, accB[1], 0, 0, 0);
      accB[2] = __builtin_amdgcn_mfma_f32_16x16x16f16(s1d2, pB1, accB[2], 0, 0, 0);
      accB[3] = __builtin_amdgcn_mfma_f32_16x16x16f16(s1d3, pB1, accB[3], 0, 0, 0);
    }

    // epilogue: direct fragment-layout stores, both tiles
    {
      int q0A = (w + (2 * p + 0) * 128) * 16;
      int q0B = (w + (2 * p + 1) * 128) * 16;
      float* oA = out + ((size_t)b * NQ_ + q0A + lq) * DM_ + 4 * quad;
      float* oB = out + ((size_t)b * NQ_ + q0B + lq) * DM_ + 4 * quad;
      #pragma unroll
      for (int dt = 0; dt < 4; ++dt) {
        *(f32x4*)(oA + 16 * dt) = accA[dt];
        *(f32x4*)(oB + 16 * dt) = accB[dt];
      }
    }

    if (p + 1 < PAIRS) {
      #pragma unroll
      for (int h = 0; h < 4; ++h) { qA[h] = qnA[h]; qB[h] = qnB[h]; }
    }
  }
}

extern "C" void kernel_launch(void* const* d_in, const int* in_sizes, int n_in,
                              void* d_out, int out_size, void* d_ws, size_t ws_size,
                              hipStream_t stream) {
  const float*         Q    = (const float*)d_in[0];
  const float*         K    = (const float*)d_in[1];
  const float*         V    = (const float*)d_in[2];
  const unsigned char* mask = (const unsigned char*)d_in[3];
  const float*         W    = (const float*)d_in[4];
  const float*         bo   = (const float*)d_in[5];
  float*               out  = (float*)d_out;

  hipLaunchKernelGGL(attn, dim3(B_ * BLK_PER_B), dim3(256), 0, stream,
                     Q, K, V, mask, W, bo, out);
}

// Round 8
// 247.403 us; speedup vs baseline: 1.0134x; 1.0134x over previous
//
#include <hip/hip_runtime.h>
#include <math.h>

typedef _Float16 half4_t __attribute__((ext_vector_type(4)));
typedef _Float16 half8_t __attribute__((ext_vector_type(8)));
typedef __fp16   fp16x2  __attribute__((ext_vector_type(2)));
typedef float    f32x4   __attribute__((ext_vector_type(4)));

#define B_   32
#define NQ_  16384
#define NK_  31
#define DM_  64
#define BLK_PER_B 64      // 2048 blocks total
#define ITERS 4           // tiles per wave
#define KSCALE 0.3606738222635048f   // 0.25 * log2(e): GEMM1 outputs log2-domain scores

#define AS1 __attribute__((address_space(1)))
#define AS3 __attribute__((address_space(3)))

static __device__ __forceinline__ half4_t cvt4(f32x4 f) {
  fp16x2 lo = __builtin_amdgcn_cvt_pkrtz(f[0], f[1]);
  fp16x2 hi = __builtin_amdgcn_cvt_pkrtz(f[2], f[3]);
  half4_t r;
  r[0] = (_Float16)lo[0]; r[1] = (_Float16)lo[1];
  r[2] = (_Float16)hi[0]; r[3] = (_Float16)hi[1];
  return r;
}

// ---------------------------------------------------------------------------
// Fused MHA + out-proj. Block = 4 waves, 48 KB LDS (16 KB VW^T + 32 KB Q ring).
// R0-R7 post-mortem: Little's law says we need ~26 KB/CU of outstanding loads
// for peak BW; register-based prefetch NEVER materialized (compiler sinks
// loads under pressure; VGPR_Count proved it 5 rounds running). This version
// uses __builtin_amdgcn_global_load_lds -- fire-and-forget DMA with NO dest
// register, so the compiler cannot sink it. Per-wave double-buffered Q ring
// in LDS; consumption gated by hand-counted s_waitcnt vmcnt(8/4) (never 0)
// + sched_barrier(0). DMA writes LDS linearly (lane*16B), so the per-lane
// GLOBAL source address is pre-swizzled (m173 pattern): LDS slot (row,cb)
// holds data(row, cb^(row&7)); fragment reads and store staging use the same
// XOR. Consumed buffer doubles as store staging -> 4 coalesced 1KB stores.
// No barriers in the main loop (buffers wave-private).
// ---------------------------------------------------------------------------
__global__ __launch_bounds__(256) void attn(
    const float* __restrict__ Q, const float* __restrict__ K,
    const float* __restrict__ V, const unsigned char* __restrict__ mraw,
    const float* __restrict__ W, const float* __restrict__ bout,
    float* __restrict__ out) {
  int b    = blockIdx.x >> 6;             // 64 blocks per batch
  int blk  = blockIdx.x & 63;
  int tid  = threadIdx.x;
  int wave = tid >> 6, lane = tid & 63;
  int lq = lane & 15, quad = lane >> 4;

  // [s][pair][lane] : 16B per lane = {vw_dt(2p), vw_dt(2p+1)}
  __shared__ half8_t lds_vw[8][2][64];
  // per-wave double-buffered Q tile / store staging, XOR-swizzled layout
  __shared__ f32x4 lds_q[4][2][16][16];

  const f32x4 fzero = {0.f, 0.f, 0.f, 0.f};
  int w = blk * 4 + wave;                 // 0..255 within batch
  const float* qbatch = Q + (size_t)b * NQ_ * DM_;

  // ---- async DMA of one 16x64 f32 Q tile into the wave's LDS ring slot ----
  auto dma_tile = [&](int it, int buf) {
    const float* qt = qbatch + (size_t)(w + it * 256) * 16 * DM_;
    #pragma unroll
    for (int j = 0; j < 4; ++j) {
      int row = 4 * j + quad;
      const float* src = qt + row * DM_ + ((lq ^ (row & 7)) << 2);
      __builtin_amdgcn_global_load_lds(
          (const AS1 void*)(const void*)src,
          (AS3 void*)(void*)((char*)&lds_q[wave][buf][0][0] + j * 1024),
          16, 0, 0);
    }
  };

  dma_tile(0, 0);   // tile 0 in flight before any prologue work

  // ---- mask word (per-wave, ballot-based; dtype sniffed from raw bytes) ----
  unsigned mb;
  {
    unsigned char c0 = 0, c1 = 0;
    if (lane < 62) { c0 = mraw[2 * lane]; c1 = mraw[2 * lane + 1]; }
    unsigned long long m3f =
        __ballot(lane < 62 && (c0 == 0x3f || c1 == 0x3f));
    unsigned long long moff =
        __ballot(lane < 62 && ((((2 * lane) & 3) != 0 && c0 != 0) || c1 != 0));
    int mode = m3f ? 2 : (moff ? 0 : 1);
    int nz = 0;
    if (lane < NK_) {
      int idx = b * NK_ + lane;
      nz = (mode == 0) ? (mraw[idx] != 0)
         : (mode == 1) ? (((const int*)mraw)[idx] != 0)
                       : (((const float*)mraw)[idx] != 0.0f);
    }
    mb = (unsigned)__ballot(nz) & 0x7fffffffu;
  }

  // ---- mask bias for GEMM1's C operand (key 31 pad auto-masked) ----
  f32x4 cbias[2];
  #pragma unroll
  for (int tt = 0; tt < 2; ++tt)
    #pragma unroll
    for (int r = 0; r < 4; ++r) {
      int key = 16 * tt + 4 * quad + r;
      cbias[tt][r] = ((mb >> key) & 1u) ? 0.0f : -1e30f;
    }

  // ---- K fragments in registers (16 VGPR), scale folded ----
  half4_t kf[2][4];
  #pragma unroll
  for (int tt = 0; tt < 2; ++tt) {
    int k = 16 * tt + lq;
    #pragma unroll
    for (int h = 0; h < 4; ++h) {
      f32x4 f = fzero;
      if (k < NK_)
        f = *(const f32x4*)(K + ((size_t)b * NK_ + k) * DM_ + 16 * h + 4 * quad);
      kf[tt][h] = cvt4(f * KSCALE);
    }
  }

  // ---- VW^T fragments for dt = wave (8 prologue MFMAs) -> LDS ----
  {
    half4_t af[8];
    #pragma unroll
    for (int s = 0; s < 8; ++s) {
      int k = 16 * (s & 1) + lq, h = s >> 1;
      f32x4 f = fzero;
      if (k < NK_)
        f = *(const f32x4*)(V + ((size_t)b * NK_ + k) * DM_ + 16 * h + 4 * quad);
      af[s] = cvt4(f);
    }
    half4_t bf[4];
    #pragma unroll
    for (int h = 0; h < 4; ++h) {
      f32x4 f = *(const f32x4*)(W + (16 * wave + lq) * DM_ + 16 * h + 4 * quad);
      bf[h] = cvt4(f);
    }
    #pragma unroll
    for (int s = 0; s < 8; ++s) {
      f32x4 m = __builtin_amdgcn_mfma_f32_16x16x16f16(af[s], bf[s >> 1],
                                                      fzero, 0, 0, 0);
      ((half4_t*)&lds_vw[s][wave >> 1][lane])[wave & 1] = cvt4(m);
    }
  }

  // ---- bias fragments; GEMM2's C-operand init (const across queries) ----
  f32x4 bias[4];
  #pragma unroll
  for (int dt = 0; dt < 4; ++dt)
    bias[dt] = *(const f32x4*)(bout + 16 * dt + 4 * quad);

  __syncthreads();   // also drains vmcnt: tile 0 resident past this point

  // ---- main loop: DMA pipeline, counted vmcnt, no barriers ----
  #pragma unroll
  for (int t = 0; t < ITERS; ++t) {
    const int buf = t & 1;

    // issue next tile's DMA first (4 vmem ops, un-sinkable)
    if (t + 1 < ITERS) dma_tile(t + 1, buf ^ 1);

    // wait for THIS tile's DMA: newer ops = stores(t-1) [4] + DMA(t+1) [4]
    if (t == 0 || t + 1 == ITERS)
      asm volatile("s_waitcnt vmcnt(4)" ::: "memory");
    else
      asm volatile("s_waitcnt vmcnt(8)" ::: "memory");
    __builtin_amdgcn_sched_barrier(0);

    // Q fragment reads from swizzled LDS tile
    half4_t qf[4];
    #pragma unroll
    for (int h = 0; h < 4; ++h)
      qf[h] = cvt4(lds_q[wave][buf][lq][(4 * h + quad) ^ (lq & 7)]);

    // GEMM1 + per-head softmax (log2-domain scores -> exp2)
    half4_t pf[8];
    #pragma unroll
    for (int h = 0; h < 4; ++h) {
      f32x4 c0 = __builtin_amdgcn_mfma_f32_16x16x16f16(kf[0][h], qf[h], cbias[0], 0, 0, 0);
      f32x4 c1 = __builtin_amdgcn_mfma_f32_16x16x16f16(kf[1][h], qf[h], cbias[1], 0, 0, 0);
      f32x4 e0, e1;
      #pragma unroll
      for (int r = 0; r < 4; ++r) {
        e0[r] = __builtin_amdgcn_exp2f(c0[r]);
        e1[r] = __builtin_amdgcn_exp2f(c1[r]);
      }
      float sum = (e0[0] + e0[1]) + (e0[2] + e0[3]) +
                  (e1[0] + e1[1]) + (e1[2] + e1[3]);
      sum += __shfl_xor(sum, 16);
      sum += __shfl_xor(sum, 32);
      float inv = (sum > 0.f) ? __builtin_amdgcn_rcpf(sum) : 0.f;
      pf[2 * h + 0] = cvt4(e0 * inv);
      pf[2 * h + 1] = cvt4(e1 * inv);
    }

    // GEMM2; C operand starts at bias
    f32x4 acc[4] = {bias[0], bias[1], bias[2], bias[3]};
    #pragma unroll
    for (int s = 0; s < 8; ++s) {
      half8_t v01 = lds_vw[s][0][lane];
      half8_t v23 = lds_vw[s][1][lane];
      half4_t a0 = __builtin_shufflevector(v01, v01, 0, 1, 2, 3);
      half4_t a1 = __builtin_shufflevector(v01, v01, 4, 5, 6, 7);
      half4_t a2 = __builtin_shufflevector(v23, v23, 0, 1, 2, 3);
      half4_t a3 = __builtin_shufflevector(v23, v23, 4, 5, 6, 7);
      acc[0] = __builtin_amdgcn_mfma_f32_16x16x16f16(a0, pf[s], acc[0], 0, 0, 0);
      acc[1] = __builtin_amdgcn_mfma_f32_16x16x16f16(a1, pf[s], acc[1], 0, 0, 0);
      acc[2] = __builtin_amdgcn_mfma_f32_16x16x16f16(a2, pf[s], acc[2], 0, 0, 0);
      acc[3] = __builtin_amdgcn_mfma_f32_16x16x16f16(a3, pf[s], acc[3], 0, 0, 0);
    }

    // store staging through the freed buffer (same swizzle), then 4x1KB stores
    #pragma unroll
    for (int dt = 0; dt < 4; ++dt)
      lds_q[wave][buf][lq][(4 * dt + quad) ^ (lq & 7)] = acc[dt];

    float* ot = out + ((size_t)b * NQ_ + (size_t)(w + t * 256) * 16) * DM_;
    #pragma unroll
    for (int j = 0; j < 4; ++j) {
      int row = 4 * j + quad;
      f32x4 ov = lds_q[wave][buf][row][lq ^ (row & 7)];
      *(f32x4*)(ot + row * DM_ + lq * 4) = ov;
    }
  }
}

extern "C" void kernel_launch(void* const* d_in, const int* in_sizes, int n_in,
                              void* d_out, int out_size, void* d_ws, size_t ws_size,
                              hipStream_t stream) {
  const float*         Q    = (const float*)d_in[0];
  const float*         K    = (const float*)d_in[1];
  const float*         V    = (const float*)d_in[2];
  const unsigned char* mask = (const unsigned char*)d_in[3];
  const float*         W    = (const float*)d_in[4];
  const float*         bo   = (const float*)d_in[5];
  float*               out  = (float*)d_out;

  hipLaunchKernelGGL(attn, dim3(B_ * BLK_PER_B), dim3(256), 0, stream,
                     Q, K, V, mask, W, bo, out);
}